// Round 8
// baseline (78.635 us; speedup 1.0000x reference)
//
#include <hip/hip_runtime.h>

// Problem constants
#define BB 8
#define CIN 16
#define COUT 64
#define HH 32
#define WW 32

// denom = 2*N_EKV*VT = 0.075. Pre-scaled log2-units:
//   x' = x*C, th' = clip(theta,1,8)*C, C = log2(e)/0.075; b1 = x'-th'
//   e2 = e1 * 2^(-0.1*C).  Reference clip(a,-50,20) == post-log
//   l = min(log2(1+2^b), B_HI) (fp32-exact; see R6 notes).
//   d >= 1.6: both l's hit B_HI -> cancel exactly. d <= -0.72: f < 5e-9 -> skip.
#define SCALE_C 19.235933878519388f /* (1/0.075)*log2(e) */
#define K2E 0.26359713811472845f    /* 2^(-0.1*SCALE_C) = e^(-4/3) */
#define B_HI 28.85390081777927f     /* 20*log2e */
#define WINLO_S (-13.849872392533959f) /* -0.72 * SCALE_C */
#define OUT_CONST (0.4804530139182014f * 0.05625f * 0.1f) /* ln2^2*ALPHA*R */

#define EXP2F(x) __builtin_amdgcn_exp2f(x)
#define LOG2F(x) __builtin_amdgcn_logf(x)

// LDS x-slice: 8 cins per phase, 10 rows (tile rows -1..8), 34 cols (-1..32)
#define XROWS 10
#define XCOLS 34
#define XPLANE (XROWS * XCOLS) // 340
#define PHASE_CINS 8
#define STAGE_ELEMS (PHASE_CINS * XPLANE) // 2720

__device__ __forceinline__ void compute9(const float* v, const float4* th03,
                                         const float4* th47, float th8, float* acc) {
    float th[9] = {th03->x, th03->y, th03->z, th03->w,
                   th47->x, th47->y, th47->z, th47->w, th8};
#pragma unroll
    for (int k = 0; k < 9; ++k) {
        float b1 = v[k] - th[k];
        if (__any(b1 > WINLO_S)) {
            float e1 = EXP2F(b1);
            float e2 = e1 * K2E;
            float l1 = fminf(LOG2F(1.0f + e1), B_HI);
            float l2 = fminf(LOG2F(1.0f + e2), B_HI);
            float a = acc[k % 3];
            a = fmaf(l1, l1, a);
            a = fmaf(-l2, l2, a);
            acc[k % 3] = a;
        }
    }
}

// Single self-contained kernel. Block mapping = R7's XCD-aware decode:
//   b = bid&7 (XCD id), tile = (bid>>3)&3, co = (bid>>8)*8 + ((bid>>5)&7)
// so the 8 co-resident blocks per CU share the same (b,tile) x-slice.
// LDS: 10.9KB x-slice (single-buffer, 2 phases of 8 cins) + 768B theta
// -> 8 blocks/CU (93KB), 8 waves/SIMD. No global loads in the K-loop.
__global__ __launch_bounds__(256, 8) void ekv_kernel(const float* __restrict__ x,
                                                     const float* __restrict__ theta,
                                                     const float* __restrict__ scale,
                                                     float* __restrict__ out) {
    int bid = blockIdx.x;
    int b = bid & 7;
    int tile = (bid >> 3) & 3;
    int co = (bid >> 8) * 8 + ((bid >> 5) & 7);

    int t = threadIdx.x;
    int ow = t & 31;
    int ohl = t >> 5;           // 0..7 within tile
    int oh = tile * 8 + ohl;

    __shared__ __align__(16) float s_x[STAGE_ELEMS]; // 10.6KB
    __shared__ __align__(16) float s_th[CIN * 12];   // 768B

    // theta prep: clip*scale, padded to 12/cin (16B rows -> b128 broadcast)
    if (t < CIN * 12) {
        int cin = t / 12;
        int j = t - cin * 12;
        float v = 0.0f;
        if (j < 9) v = fminf(fmaxf(theta[co * (CIN * 9) + cin * 9 + j], 1.0f), 8.0f) * SCALE_C;
        s_th[t] = v;
    }

    const float* xb = x + (size_t)b * (CIN * HH * WW);
    float acc[3] = {0.0f, 0.0f, 0.0f};
    float sc = scale[0] * (OUT_CONST);

    int pixbase = ohl * XCOLS + ow; // within a plane; +dy*34+dx taps

#pragma unroll 1
    for (int phase = 0; phase < 2; ++phase) {
        int cinBase = phase * PHASE_CINS;
        if (phase) __syncthreads(); // protect s_x reuse before restaging

        // Stage 8 cins x 10 rows x 34 cols, bounds-checked, pre-scaled.
#pragma unroll 1
        for (int i = t; i < STAGE_ELEMS; i += 256) {
            int cinL = i / XPLANE;
            int rem = i - cinL * XPLANE;
            int r = rem / XCOLS;
            int c = rem - r * XCOLS;
            int gy = tile * 8 + r - 1;
            int gx = c - 1;
            float v = 0.0f;
            if ((unsigned)gy < HH && (unsigned)gx < WW)
                v = xb[((cinBase + cinL) * HH + gy) * WW + gx] * SCALE_C;
            s_x[i] = v;
        }
        __syncthreads();

        // K-loop over this phase's 8 cins: pure LDS + VALU, ping-pong regs.
        float va[9], vb[9];
        {
            const float* p = s_x + pixbase;
#pragma unroll
            for (int dy = 0; dy < 3; ++dy)
#pragma unroll
                for (int dx = 0; dx < 3; ++dx) va[dy * 3 + dx] = p[dy * XCOLS + dx];
        }
#pragma unroll 1
        for (int cl = 0; cl < PHASE_CINS; cl += 2) {
            {
                const float* p = s_x + (cl + 1) * XPLANE + pixbase;
#pragma unroll
                for (int dy = 0; dy < 3; ++dy)
#pragma unroll
                    for (int dx = 0; dx < 3; ++dx) vb[dy * 3 + dx] = p[dy * XCOLS + dx];
            }
            {
                int cin = cinBase + cl;
                const float4* th03 = (const float4*)&s_th[cin * 12];
                const float4* th47 = th03 + 1;
                compute9(va, th03, th47, s_th[cin * 12 + 8], acc);
            }
            {
                int nc = cl + 2 < PHASE_CINS ? cl + 2 : PHASE_CINS - 1; // harmless re-read
                const float* p = s_x + nc * XPLANE + pixbase;
#pragma unroll
                for (int dy = 0; dy < 3; ++dy)
#pragma unroll
                    for (int dx = 0; dx < 3; ++dx) va[dy * 3 + dx] = p[dy * XCOLS + dx];
            }
            {
                int cin = cinBase + cl + 1;
                const float4* th03 = (const float4*)&s_th[cin * 12];
                const float4* th47 = th03 + 1;
                compute9(vb, th03, th47, s_th[cin * 12 + 8], acc);
            }
        }
    }

    out[(((size_t)b * COUT + co) * HH + oh) * WW + ow] =
        (acc[0] + acc[1] + acc[2]) * sc;
}

extern "C" void kernel_launch(void* const* d_in, const int* in_sizes, int n_in,
                              void* d_out, int out_size, void* d_ws, size_t ws_size,
                              hipStream_t stream) {
    const float* x = (const float*)d_in[0];
    const float* theta = (const float*)d_in[1];
    const float* scale = (const float*)d_in[2];
    float* out = (float*)d_out;
    (void)d_ws; (void)ws_size; (void)in_sizes; (void)n_in; (void)out_size;

    ekv_kernel<<<BB * 4 * COUT, 256, 0, stream>>>(x, theta, scale, out);
}